// Round 4
// baseline (242.801 us; speedup 1.0000x reference)
//
#include <hip/hip_runtime.h>
#include <math.h>

#define MEM  2048
#define NT   256
#define NT1  192

struct Params {
    const float *lc, *rc, *lh, *rh, *S, *w;
    const float *Wh_w, *Wh_b, *Us_w, *Us_b, *ma_w, *ma_b;
    const float *ilh_w, *ilh_b, *irh_w, *irh_b;
    const float *lflh_w, *lflh_b, *lfrh_w, *lfrh_b;
    const float *rflh_w, *rflh_b, *rfrh_w, *rfrh_b;
    const float *ulh_w, *ulh_b, *urh_w, *urh_b;
    float *pl, *pr, *wml, *wmr, *out;
};

__device__ __forceinline__ float dot4(float4 a, float4 b) {
    return a.x * b.x + a.y * b.y + a.z * b.z + a.w * b.w;
}

__device__ __forceinline__ float wave_reduce(float v) {
#pragma unroll
    for (int off = 32; off > 0; off >>= 1)
        v += __shfl_down(v, off, 64);
    return v;
}

// fast tanh/sigmoid via v_exp; |err| ~1e-6 vs libm, tolerance is 3.9e-3.
__device__ __forceinline__ float tanh_fast(float x) {
    x = fminf(15.0f, fmaxf(-15.0f, x));
    const float e = __expf(2.0f * x);
    return (e - 1.0f) / (e + 1.0f);
}
__device__ __forceinline__ float sigmoid_fast(float x) {
    return 1.0f / (1.0f + __expf(-x));
}

// ---- k1: one block per row (grid=2048), 3 waves, one matrix stream per wave.
// wave0: wh row  -> awl = wh·lh, awr = wh·rh
// wave1: us row  -> aus = us·S
// wave2: ma row  -> aml = ma·lh, amr = ma·rh
// Each lane: burst-load 8 weight float4 (all in flight), then consume against
// L1-hot x vectors. No shallow load-wait-consume cycles.
__global__ __launch_bounds__(NT1, 2) void k1(Params p)
{
    __shared__ float s_par[5];

    const int t   = threadIdx.x;
    const int wv  = t >> 6, ln = t & 63;
    const int row = blockIdx.x;

    const float4* l4 = (const float4*)p.lh;
    const float4* r4 = (const float4*)p.rh;
    const float4* s4 = (const float4*)p.S;

    if (wv == 0) {
        const float4* w4 = (const float4*)(p.Wh_w + (size_t)row * MEM);
        float4 wb[8];
#pragma unroll
        for (int j = 0; j < 8; ++j) wb[j] = w4[ln + 64 * j];
        float awl = 0.f, awr = 0.f;
#pragma unroll
        for (int j = 0; j < 8; ++j) {
            awl += dot4(wb[j], l4[ln + 64 * j]);
            awr += dot4(wb[j], r4[ln + 64 * j]);
        }
        awl = wave_reduce(awl);
        awr = wave_reduce(awr);
        if (ln == 0) { s_par[0] = awl; s_par[1] = awr; }
    } else if (wv == 1) {
        const float4* u4 = (const float4*)(p.Us_w + (size_t)row * MEM);
        float4 ub[8];
#pragma unroll
        for (int j = 0; j < 8; ++j) ub[j] = u4[ln + 64 * j];
        float aus = 0.f;
#pragma unroll
        for (int j = 0; j < 8; ++j)
            aus += dot4(ub[j], s4[ln + 64 * j]);
        aus = wave_reduce(aus);
        if (ln == 0) s_par[2] = aus;
    } else {
        const float4* m4 = (const float4*)(p.ma_w + (size_t)row * MEM);
        float4 mb[8];
#pragma unroll
        for (int j = 0; j < 8; ++j) mb[j] = m4[ln + 64 * j];
        float aml = 0.f, amr = 0.f;
#pragma unroll
        for (int j = 0; j < 8; ++j) {
            aml += dot4(mb[j], l4[ln + 64 * j]);
            amr += dot4(mb[j], r4[ln + 64 * j]);
        }
        aml = wave_reduce(aml);
        amr = wave_reduce(amr);
        if (ln == 0) { s_par[3] = aml; s_par[4] = amr; }
    }
    __syncthreads();

    if (t == 0) {
        const float us  = s_par[2] + p.Us_b[row];
        const float whb = p.Wh_b[row];
        const float ml  = tanh_fast(s_par[0] + whb + us);
        const float mr  = tanh_fast(s_par[1] + whb + us);
        p.pl[row] = s_par[3];
        p.pr[row] = s_par[4];
        const float wj = p.w[row];
        p.wml[row] = wj * ml;
        p.wmr[row] = wj * mr;
    }
}

// ---- kmid: ONE block. Global reduce of wml/wmr -> alpha; then writes
// xa = tanh(al*pl + ma_b), xb = tanh(ar*pr + ma_b) IN PLACE over wml/wmr.
// Removes the block-redundant alpha/tanh prologue from all 2048 k2 blocks.
__global__ __launch_bounds__(NT) void kmid(Params p)
{
    __shared__ float s_red[4][2];
    __shared__ float s_al[2];

    const int t  = threadIdx.x;
    const int wv = t >> 6, ln = t & 63;

    const float4* wl4 = (const float4*)p.wml;
    const float4* wr4 = (const float4*)p.wmr;
    const float4 a0 = wl4[t], a1 = wl4[t + NT];
    const float4 b0 = wr4[t], b1 = wr4[t + NT];
    float el = a0.x + a0.y + a0.z + a0.w + a1.x + a1.y + a1.z + a1.w;
    float er = b0.x + b0.y + b0.z + b0.w + b1.x + b1.y + b1.z + b1.w;
    el = wave_reduce(el);
    er = wave_reduce(er);
    if (ln == 0) { s_red[wv][0] = el; s_red[wv][1] = er; }
    __syncthreads();
    if (t == 0) {
        const float e0 = s_red[0][0] + s_red[1][0] + s_red[2][0] + s_red[3][0];
        const float e1 = s_red[0][1] + s_red[1][1] + s_red[2][1] + s_red[3][1];
        const float d  = e0 + e1;
        s_al[0] = e0 / d;
        s_al[1] = e1 / d;
    }
    __syncthreads();
    const float al = s_al[0];
    const float ar = s_al[1];

    // all wml/wmr reads above completed before the barrier -> safe to overwrite
    const float4* p4 = (const float4*)p.pl;
    const float4* q4 = (const float4*)p.pr;
    const float4* b4 = (const float4*)p.ma_b;
    float4* xa4 = (float4*)p.wml;
    float4* xb4 = (float4*)p.wmr;
#pragma unroll
    for (int h = 0; h < 2; ++h) {
        const int i = t + h * NT;
        const float4 pp = p4[i];
        const float4 qq = q4[i];
        const float4 bb = b4[i];
        float4 xa, xb;
        xa.x = tanh_fast(al * pp.x + bb.x); xb.x = tanh_fast(ar * qq.x + bb.x);
        xa.y = tanh_fast(al * pp.y + bb.y); xb.y = tanh_fast(ar * qq.y + bb.y);
        xa.z = tanh_fast(al * pp.z + bb.z); xb.z = tanh_fast(ar * qq.z + bb.z);
        xa.w = tanh_fast(al * pp.w + bb.w); xb.w = tanh_fast(ar * qq.w + bb.w);
        xa4[i] = xa;
        xb4[i] = xb;
    }
}

// ---- k2: one block per row (grid=2048), pure streaming.
// wave wv owns gate pair: burst 16 weight float4 in flight, then consume
// against xa/xb read directly from global (L1-hot, same addrs every block).
// No LDS staging, no syncs until the final 4-value combine.
__global__ __launch_bounds__(NT, 2) void k2(Params p)
{
    __shared__ float s_g[4];

    const int t   = threadIdx.x;
    const int wv  = t >> 6, ln = t & 63;
    const int row = blockIdx.x;

    // per-row scalars (wave-uniform -> s_load), issued before the bursts
    const float bI  = p.ilh_b[row]  + p.irh_b[row];
    const float bLF = p.lflh_b[row] + p.lfrh_b[row];
    const float bRF = p.rflh_b[row] + p.rfrh_b[row];
    const float bU  = p.ulh_b[row]  + p.urh_b[row];
    const float lcv = p.lc[row], rcv = p.rc[row];

    const float *wlp, *wrp;
    if      (wv == 0) { wlp = p.ilh_w;  wrp = p.irh_w;  }
    else if (wv == 1) { wlp = p.lflh_w; wrp = p.lfrh_w; }
    else if (wv == 2) { wlp = p.rflh_w; wrp = p.rfrh_w; }
    else              { wlp = p.ulh_w;  wrp = p.urh_w;  }

    const float4* wl4  = (const float4*)(wlp + (size_t)row * MEM);
    const float4* wr4  = (const float4*)(wrp + (size_t)row * MEM);
    const float4* xag4 = (const float4*)p.wml;   // xa (written by kmid)
    const float4* xbg4 = (const float4*)p.wmr;   // xb

    float4 ab[8], bb[8];
#pragma unroll
    for (int j = 0; j < 8; ++j) ab[j] = wl4[ln + 64 * j];
#pragma unroll
    for (int j = 0; j < 8; ++j) bb[j] = wr4[ln + 64 * j];

    float accA = 0.f, accB = 0.f;
#pragma unroll
    for (int j = 0; j < 8; ++j) accA += dot4(ab[j], xag4[ln + 64 * j]);
#pragma unroll
    for (int j = 0; j < 8; ++j) accB += dot4(bb[j], xbg4[ln + 64 * j]);

    const float g = wave_reduce(accA + accB);
    if (ln == 0) s_g[wv] = g;
    __syncthreads();

    if (t == 0) {
        const float ig  = sigmoid_fast(s_g[0] + bI);
        const float lfg = sigmoid_fast(s_g[1] + bLF);
        const float rfg = sigmoid_fast(s_g[2] + bRF);
        const float ug  = tanh_fast(s_g[3] + bU);
        const float c   = ig * ug + lfg * lcv + rfg * rcv;
        p.out[row]       = c;
        p.out[MEM + row] = tanh_fast(c);
    }
}

extern "C" void kernel_launch(void* const* d_in, const int* in_sizes, int n_in,
                              void* d_out, int out_size, void* d_ws, size_t ws_size,
                              hipStream_t stream)
{
    Params h;
    h.lc = (const float*)d_in[0];
    h.lh = (const float*)d_in[1];
    h.rc = (const float*)d_in[2];
    h.rh = (const float*)d_in[3];
    h.S  = (const float*)d_in[4];
    h.w  = (const float*)d_in[5];
    h.Wh_w   = (const float*)d_in[6];   h.Wh_b   = (const float*)d_in[7];
    h.Us_w   = (const float*)d_in[8];   h.Us_b   = (const float*)d_in[9];
    h.ma_w   = (const float*)d_in[10];  h.ma_b   = (const float*)d_in[11];
    h.ilh_w  = (const float*)d_in[12];  h.ilh_b  = (const float*)d_in[13];
    h.irh_w  = (const float*)d_in[14];  h.irh_b  = (const float*)d_in[15];
    h.lflh_w = (const float*)d_in[16];  h.lflh_b = (const float*)d_in[17];
    h.lfrh_w = (const float*)d_in[18];  h.lfrh_b = (const float*)d_in[19];
    h.rflh_w = (const float*)d_in[20];  h.rflh_b = (const float*)d_in[21];
    h.rfrh_w = (const float*)d_in[22];  h.rfrh_b = (const float*)d_in[23];
    h.ulh_w  = (const float*)d_in[24];  h.ulh_b  = (const float*)d_in[25];
    h.urh_w  = (const float*)d_in[26];  h.urh_b  = (const float*)d_in[27];

    float* ws = (float*)d_ws;
    h.pl  = ws;
    h.pr  = ws + MEM;
    h.wml = ws + 2 * MEM;   // becomes xa after kmid
    h.wmr = ws + 3 * MEM;   // becomes xb after kmid
    h.out = (float*)d_out;

    k1  <<<MEM, NT1, 0, stream>>>(h);
    kmid<<<1,   NT,  0, stream>>>(h);
    k2  <<<MEM, NT,  0, stream>>>(h);
}